// Round 11
// baseline (2473.734 us; speedup 1.0000x reference)
//
#include <hip/hip_runtime.h>
#include <hip/hip_bf16.h>
#include <math.h>

// Problem constants
#define BN   128      // batch
#define CIN  3
#define HCn  32       // hidden channels (ODE state)
#define HHCn 128      // inner hidden channels
#define NPX  1024     // 32*32
#define PN   4        // pieces
#define NCLS 10

// 4-row strip geometry: 8 strips/image, padded px = 6*34 = 204 (rounded 208).
#define PPAD  204
#define PPADR 208
#define PLROW 8       // ushorts per plane row (8 ic)
#define PLSZ  1664    // 208 * 8 ushorts per plane
#define H2P   136     // h2 pitch (ushorts): 272B rows

typedef short bf16x8 __attribute__((ext_vector_type(8)));
typedef float f32x4  __attribute__((ext_vector_type(4)));
typedef float f32x16 __attribute__((ext_vector_type(16)));

// ---- fast transcendentals (HW v_exp/v_log/v_rcp; err ~1e-7, threshold 0.2) ----
__device__ __forceinline__ float softplus_f(float x) {
    return fmaxf(x, 0.f) + __logf(1.f + __expf(-fabsf(x)));
}
__device__ __forceinline__ float tanh_fast(float x) {
    float e = __expf(-2.f * fabsf(x));
    float r = 1.f - 2.f * e * __builtin_amdgcn_rcpf(1.f + e);   // tanh(|x|)
    unsigned u = (__float_as_uint(r) & 0x7fffffffu) | (__float_as_uint(x) & 0x80000000u);
    return __uint_as_float(u);
}
__device__ __forceinline__ unsigned int f2bf(float f) {   // RNE fp32->bf16 bits
    unsigned int u = __float_as_uint(f);
    return (u + 0x7fffu + ((u >> 16) & 1u)) >> 16;
}
__device__ __forceinline__ float bf2f(unsigned int h) {
    return __uint_as_float(h << 16);
}
__device__ __forceinline__ void pack2(float a, float b, unsigned int& hi, unsigned int& lo) {
    __hip_bfloat162 h2 = __float22bfloat162_rn(float2{a, b});
    unsigned int h = *reinterpret_cast<unsigned int*>(&h2);
    float ha = __uint_as_float(h << 16);
    float hb = __uint_as_float(h & 0xffff0000u);
    __hip_bfloat162 l2 = __float22bfloat162_rn(float2{a - ha, b - hb});
    hi = h;
    lo = *reinterpret_cast<unsigned int*>(&l2);
}

// ---------------- augment ----------------
__global__ __launch_bounds__(256) void k_aug(
    const float* __restrict__ x, const float* __restrict__ aW,
    const float* __restrict__ ab, float* __restrict__ z)
{
    const int b = blockIdx.x, tid = threadIdx.x;
    const size_t xb = (size_t)b * CIN * NPX;
    const size_t zb = (size_t)b * HCn * NPX;
    float xv[CIN][4];
#pragma unroll
    for (int c = 0; c < CIN; c++)
#pragma unroll
        for (int j = 0; j < 4; j++)
            xv[c][j] = x[xb + c * NPX + tid + 256 * j];
    for (int o = 0; o < HCn; o++) {
        float w0 = aW[o * 3], w1 = aW[o * 3 + 1], w2 = aW[o * 3 + 2], bb = ab[o];
#pragma unroll
        for (int j = 0; j < 4; j++) {
            float v = fmaf(w0, xv[0][j], fmaf(w1, xv[1][j], fmaf(w2, xv[2][j], bb)));
            z[zb + (size_t)o * NPX + tid + 256 * j] = v;
        }
    }
}

// ---------------- pack W2 into 32x32x16 MFMA A-frag order, bf16 hi/lo -------
// layout: [p][sh][kc][kk][ocg32][lane][j]; oc = ocg32*32+(lane&31),
// ic = kc*32 + kk*16 + (lane>>5)*8 + j
__global__ __launch_bounds__(256) void k_packW2(
    const float* __restrict__ W2, unsigned short* __restrict__ whi,
    unsigned short* __restrict__ wlo)
{
    int t = blockIdx.x * 256 + threadIdx.x;          // < 589824
    int j    = t & 7;
    int lane = (t >> 3) & 63;
    int ocg  = (t >> 9) & 3;                         // ocg32
    int kk   = (t >> 11) & 1;
    int kc   = (t >> 12) & 3;
    int p9s  = t >> 14;                              // p*9 + sh
    int sh = p9s % 9, p = p9s / 9;
    int dy = sh / 3, dx = sh % 3;
    int oc = ocg * 32 + (lane & 31);
    int ic = kc * 32 + kk * 16 + (lane >> 5) * 8 + j;
    float v = W2[((((size_t)p * HHCn + oc) * HHCn + ic) * 3 + dy) * 3 + dx];
    unsigned int hi = f2bf(v);
    whi[t] = (unsigned short)hi;
    wlo[t] = (unsigned short)f2bf(v - bf2f(hi));
}

// ---------------- pack W1 ----------------
__global__ __launch_bounds__(256) void k_packW1(
    const float* __restrict__ W1, unsigned short* __restrict__ whi,
    unsigned short* __restrict__ wlo)
{
    int t = blockIdx.x * 256 + threadIdx.x;          // < 16384
    int j = t & 7, lane = (t >> 3) & 63, m = (t >> 9) & 1, kc = (t >> 10) & 3, p = t >> 12;
    int oc = kc * 32 + m * 16 + (lane & 15);
    int ic = (lane >> 4) * 8 + j;
    float v = W1[((size_t)p * HHCn + oc) * 33 + 1 + ic];
    unsigned int hi = f2bf(v);
    whi[t] = (unsigned short)hi;
    wlo[t] = (unsigned short)f2bf(v - bf2f(hi));
}

// ---------------- pack W3 ----------------
__global__ __launch_bounds__(256) void k_packW3(
    const float* __restrict__ W3, unsigned short* __restrict__ whi,
    unsigned short* __restrict__ wlo)
{
    int t = blockIdx.x * 256 + threadIdx.x;          // < 16384
    int j = t & 7, lane = (t >> 3) & 63, kk = (t >> 9) & 3, m = (t >> 11) & 1, p = t >> 12;
    int st = m * 16 + (lane & 15);
    int ic = kk * 32 + (lane >> 4) * 8 + j;
    float v = W3[((size_t)p * HCn + st) * HHCn + ic];
    unsigned int hi = f2bf(v);
    whi[t] = (unsigned short)hi;
    wlo[t] = (unsigned short)f2bf(v - bf2f(hi));
}

// ---------------- fused f-eval: conv1(16x16) -> conv3x3(32x32) -> convw3 ----
// grid (8 strips, BN), 512 thr. conv3: wave = 64oc x 32px (2 ocW x 4 pxW),
// acc[ocg][kk] = 4 independent chains (ILP), B reads halved by 2-ocg reuse.
__global__ __launch_bounds__(512, 4) void k_fused(
    const float* __restrict__ z_in, const float* __restrict__ kb_in, float alpha,
    const float* __restrict__ b1p, const float* __restrict__ W1t, float t,
    const unsigned short* __restrict__ w1h, const unsigned short* __restrict__ w1l,
    const unsigned short* __restrict__ w2h, const unsigned short* __restrict__ w2l,
    const float* __restrict__ b2p,
    const unsigned short* __restrict__ w3h, const unsigned short* __restrict__ w3l,
    const float* __restrict__ b3p,
    float* __restrict__ kb_out, float* __restrict__ accb, float* __restrict__ z_out,
    int mode)
{
    const int strip = blockIdx.x, b = blockIdx.y;
    const int tid = threadIdx.x, lane = tid & 63, wid = tid >> 6;
    const int ln15 = lane & 15, lg = lane >> 4;
    const int kl8 = lg * 8, kl4 = lg * 4;

    __shared__ __align__(16) unsigned short S[39936];   // 79.87 KB
    unsigned short* zinh = S;                            // 6656
    unsigned short* zinl = S + 6656;
    unsigned short* xh0  = S + 13312;
    unsigned short* xl0  = S + 19968;
    unsigned short* xh1  = S + 26624;
    unsigned short* xl1  = S + 33280;
    unsigned short* h2qh = S;                            // alias zin+X0 (freed)
    unsigned short* h2ql = S + 8704;

    const size_t zbB = (size_t)b * HCn * NPX;
    const int strip0 = strip * 4;

    // ---- phase 0: stage zin = bf16hl(z + alpha*k), 32ic x 204 padded px ----
    {
        const int ic0 = wid * 4;
        const int pl  = wid >> 1;
        const int sl  = (wid & 1) * 4;
#pragma unroll
        for (int it = 0; it < 4; it++) {
            int ppad = it * 64 + lane;
            int prow = ppad / 34, pcol = ppad - prow * 34;
            int gy = strip0 + prow - 1, gx = pcol - 1;
            bool okm = (ppad < PPAD) && (gy >= 0) && (gy < 32) && (gx >= 0) && (gx < 32);
            int gsrc = gy * 32 + gx;
            float v[4];
#pragma unroll
            for (int c = 0; c < 4; c++)
                v[c] = okm ? z_in[zbB + (size_t)(ic0 + c) * NPX + gsrc] : 0.f;
            if (alpha != 0.f) {
#pragma unroll
                for (int c = 0; c < 4; c++)
                    if (okm) v[c] = fmaf(alpha, kb_in[zbB + (size_t)(ic0 + c) * NPX + gsrc], v[c]);
            }
            unsigned int h01, l01, h23, l23;
            pack2(v[0], v[1], h01, l01);
            pack2(v[2], v[3], h23, l23);
            if (ppad < PPADR) {
                int off = pl * PLSZ + ppad * PLROW + sl;
                *(uint2*)(zinh + off) = make_uint2(h01, h23);
                *(uint2*)(zinl + off) = make_uint2(l01, l23);
            }
        }
    }

    // conv3 wave roles: ocW = wid&1 (64 oc), pxW = wid>>1 (32 px)
    const int wocp = wid & 1;                // oc pair base: ocg32 = wocp*2 + o
    const int wpx  = (wid >> 1) * 32;        // px group base
    const int ln31 = lane & 31, l5 = lane >> 5;
    const int b32off = (((wpx + ln31) >> 5) * 34 + ((wpx + ln31) & 31)) * PLROW;

    f32x16 acc[2][2];                        // [ocg][kk] — 4 independent chains
#pragma unroll
    for (int o = 0; o < 2; o++)
#pragma unroll
        for (int kk = 0; kk < 2; kk++) acc[o][kk] = (f32x16)(0.f);

    f32x4 c1[2][2];

    // conv1 MFMA (16x16x32) for chunk kc -> c1
    auto do_conv1 = [&](int kc) {
        const unsigned short* w1hb = w1h + (size_t)kc * 1024 + lane * 8;
        const unsigned short* w1lb = w1l + (size_t)kc * 1024 + lane * 8;
        bf16x8 a1h0 = *(const bf16x8*)w1hb, a1h1 = *(const bf16x8*)(w1hb + 512);
        bf16x8 a1l0 = *(const bf16x8*)w1lb, a1l1 = *(const bf16x8*)(w1lb + 512);
#pragma unroll
        for (int m = 0; m < 2; m++)
#pragma unroll
            for (int ni = 0; ni < 2; ni++) c1[m][ni] = (f32x4)(0.f);
#pragma unroll
        for (int ni = 0; ni < 2; ni++) {
            int n = wid + 8 * ni;
            if (ni == 0 || wid < 5) {
                int roff = lg * PLSZ + (n * 16 + ln15) * PLROW;
                bf16x8 bh = *(const bf16x8*)(zinh + roff);
                bf16x8 bl = *(const bf16x8*)(zinl + roff);
                c1[0][ni] = __builtin_amdgcn_mfma_f32_16x16x32_bf16(a1h0, bh, c1[0][ni], 0, 0, 0);
                c1[0][ni] = __builtin_amdgcn_mfma_f32_16x16x32_bf16(a1h0, bl, c1[0][ni], 0, 0, 0);
                c1[0][ni] = __builtin_amdgcn_mfma_f32_16x16x32_bf16(a1l0, bh, c1[0][ni], 0, 0, 0);
                c1[1][ni] = __builtin_amdgcn_mfma_f32_16x16x32_bf16(a1h1, bh, c1[1][ni], 0, 0, 0);
                c1[1][ni] = __builtin_amdgcn_mfma_f32_16x16x32_bf16(a1h1, bl, c1[1][ni], 0, 0, 0);
                c1[1][ni] = __builtin_amdgcn_mfma_f32_16x16x32_bf16(a1l1, bh, c1[1][ni], 0, 0, 0);
            }
        }
    };

    // softplus + pack + write X chunk kc into (xh_, xl_)
    auto do_writeX = [&](int kc, unsigned short* xh_, unsigned short* xl_) {
        float eb[2][4];
#pragma unroll
        for (int m = 0; m < 2; m++)
#pragma unroll
            for (int r = 0; r < 4; r++) {
                int oc = kc * 32 + m * 16 + kl4 + r;
                eb[m][r] = b1p[oc] + t * W1t[oc * 33];
            }
#pragma unroll
        for (int ni = 0; ni < 2; ni++) {
            int n = wid + 8 * ni;
            if (ni == 0 || wid < 5) {
                int ppad = n * 16 + ln15;
                int prow = ppad / 34, pcol = ppad - prow * 34;
                int gy = strip0 + prow - 1;
                bool zero = (pcol == 0) || (pcol == 33) || (gy < 0) || (gy >= 32);
#pragma unroll
                for (int m = 0; m < 2; m++) {
                    float v[4];
#pragma unroll
                    for (int r = 0; r < 4; r++)
                        v[r] = zero ? 0.f : softplus_f(c1[m][ni][r] + eb[m][r]);
                    unsigned int h01, l01, h23, l23;
                    pack2(v[0], v[1], h01, l01);
                    pack2(v[2], v[3], h23, l23);
                    int off = (m * 2 + (kl4 >> 3)) * PLSZ + ppad * PLROW + (kl4 & 7);
                    *(uint2*)(xh_ + off) = make_uint2(h01, h23);
                    *(uint2*)(xl_ + off) = make_uint2(l01, l23);
                }
            }
        }
    };

    // conv3 partial (32x32x16) for chunk kc from (xh_, xl_)
    auto do_conv3 = [&](int kc, const unsigned short* xh_, const unsigned short* xl_) {
#pragma unroll
        for (int sh = 0; sh < 9; sh++) {
            const int shoff = ((sh / 3) * 34 + (sh % 3)) * PLROW;
#pragma unroll
            for (int kk = 0; kk < 2; kk++) {
                const size_t wb0 = ((((size_t)(sh * 4 + kc) * 2 + kk) * 4 + wocp * 2) * 64 + lane) * 8;
                bf16x8 ah0 = *(const bf16x8*)(w2h + wb0);
                bf16x8 al0 = *(const bf16x8*)(w2l + wb0);
                bf16x8 ah1 = *(const bf16x8*)(w2h + wb0 + 512);
                bf16x8 al1 = *(const bf16x8*)(w2l + wb0 + 512);
                const int soff = (kk * 2 + l5) * PLSZ + b32off + shoff;
                bf16x8 bh = *(const bf16x8*)(xh_ + soff);
                bf16x8 bl = *(const bf16x8*)(xl_ + soff);
                acc[0][kk] = __builtin_amdgcn_mfma_f32_32x32x16_bf16(ah0, bh, acc[0][kk], 0, 0, 0);
                acc[1][kk] = __builtin_amdgcn_mfma_f32_32x32x16_bf16(ah1, bh, acc[1][kk], 0, 0, 0);
                acc[0][kk] = __builtin_amdgcn_mfma_f32_32x32x16_bf16(ah0, bl, acc[0][kk], 0, 0, 0);
                acc[1][kk] = __builtin_amdgcn_mfma_f32_32x32x16_bf16(ah1, bl, acc[1][kk], 0, 0, 0);
                acc[0][kk] = __builtin_amdgcn_mfma_f32_32x32x16_bf16(al0, bh, acc[0][kk], 0, 0, 0);
                acc[1][kk] = __builtin_amdgcn_mfma_f32_32x32x16_bf16(al1, bh, acc[1][kk], 0, 0, 0);
            }
        }
    };

    __syncthreads();                 // zin staged
    do_conv1(0);
    do_writeX(0, xh0, xl0);          // X0 <- chunk 0
    __syncthreads();

    // region kc=0: conv1(1) | write X1 | conv3(0) on X0
    do_conv1(1); do_writeX(1, xh1, xl1); do_conv3(0, xh0, xl0);
    __syncthreads();
    // region kc=1: conv1(2) | write X0 | conv3(1) on X1
    do_conv1(2); do_writeX(2, xh0, xl0); do_conv3(1, xh1, xl1);
    __syncthreads();
    // region kc=2: conv1(3) | write X1 | conv3(2) on X0
    do_conv1(3); do_writeX(3, xh1, xl1); do_conv3(2, xh0, xl0);
    __syncthreads();
    // region kc=3: conv3(3) on X1
    do_conv3(3, xh1, xl1);

    // ---- convw3 + RK4 epilogue, per 64-px half ----
    // C 32x32 mapping: px = lane&31, oc = (r&3) + 8*(r>>2) + 4*(lane>>5)
    float bb2r[2][16];
#pragma unroll
    for (int o = 0; o < 2; o++)
#pragma unroll
        for (int r = 0; r < 16; r++)
            bb2r[o][r] = b2p[(wocp * 2 + o) * 32 + (r & 3) + 8 * (r >> 2) + 4 * l5];

    const size_t obB = (size_t)b * HCn * NPX + strip * 128;
    const int m3 = wid & 1, n4 = wid >> 1;
    float bb3[4];
#pragma unroll
    for (int r = 0; r < 4; r++) bb3[r] = b3p[m3 * 16 + kl4 + r];

#pragma unroll
    for (int q = 0; q < 2; q++) {
        __syncthreads();   // q=0: conv3(3) done; h2 aliases zin+X0 (X1 untouched)
        if ((wid >> 2) == q) {             // waves whose 32px lie in this half
            const int pxl = ((wid >> 1) & 1) * 32 + ln31;   // 0..63 within half
#pragma unroll
            for (int o = 0; o < 2; o++) {
                f32x16 a = acc[o][0] + acc[o][1];
#pragma unroll
                for (int qd = 0; qd < 4; qd++) {
                    float v[4];
#pragma unroll
                    for (int jj = 0; jj < 4; jj++)
                        v[jj] = softplus_f(a[qd * 4 + jj] + bb2r[o][qd * 4 + jj]);
                    unsigned int h01, l01, h23, l23;
                    pack2(v[0], v[1], h01, l01);
                    pack2(v[2], v[3], h23, l23);
                    int off = pxl * H2P + (wocp * 2 + o) * 32 + 8 * qd + 4 * l5;
                    *(uint2*)(h2qh + off) = make_uint2(h01, h23);
                    *(uint2*)(h2ql + off) = make_uint2(l01, l23);
                }
            }
        }
        __syncthreads();
        // convw3: [32st x 128K] x h2q[128K x 64px]; 1 tile per wave (16x16x32)
        f32x4 c3 = (f32x4)(0.f);
#pragma unroll
        for (int kk = 0; kk < 4; kk++) {
            const unsigned short* a3hb = w3h + (size_t)(m3 * 4 + kk) * 512 + lane * 8;
            const unsigned short* a3lb = w3l + (size_t)(m3 * 4 + kk) * 512 + lane * 8;
            bf16x8 a3h = *(const bf16x8*)a3hb;
            bf16x8 a3l = *(const bf16x8*)a3lb;
            bf16x8 bh = *(const bf16x8*)(h2qh + (n4 * 16 + ln15) * H2P + kk * 32 + kl8);
            bf16x8 bl = *(const bf16x8*)(h2ql + (n4 * 16 + ln15) * H2P + kk * 32 + kl8);
            c3 = __builtin_amdgcn_mfma_f32_16x16x32_bf16(a3h, bh, c3, 0, 0, 0);
            c3 = __builtin_amdgcn_mfma_f32_16x16x32_bf16(a3h, bl, c3, 0, 0, 0);
            c3 = __builtin_amdgcn_mfma_f32_16x16x32_bf16(a3l, bh, c3, 0, 0, 0);
        }
#pragma unroll
        for (int r = 0; r < 4; r++) {
            int st = m3 * 16 + kl4 + r;
            float v = tanh_fast(c3[r] + bb3[r]);
            size_t i = obB + (size_t)st * NPX + q * 64 + n4 * 16 + ln15;
            if (mode == 0)      { kb_out[i] = v; accb[i] = v; }
            else if (mode == 1) { kb_out[i] = v; accb[i] += 2.f * v; }
            else                { z_out[i] = z_in[i] + (accb[i] + v) * (1.f / 6.f); }
        }
    }
}

// ---------------- readout ----------------
__global__ __launch_bounds__(256) void k_logits(
    const float* __restrict__ z, const float* __restrict__ roW,
    const float* __restrict__ rob, float* __restrict__ logits)
{
    const int b = blockIdx.x, tid = threadIdx.x;
    float p[NCLS];
#pragma unroll
    for (int c = 0; c < NCLS; c++) p[c] = 0.f;
    const float* zp = z + (size_t)b * 32768;
    for (int i = tid; i < 32768; i += 256) {
        float zv = zp[i];
#pragma unroll
        for (int c = 0; c < NCLS; c++) p[c] = fmaf(zv, roW[(size_t)c * 32768 + i], p[c]);
    }
#pragma unroll
    for (int c = 0; c < NCLS; c++)
        for (int off = 32; off > 0; off >>= 1) p[c] += __shfl_down(p[c], off, 64);
    __shared__ float red[4][NCLS];
    int wid = tid >> 6, lane = tid & 63;
    if (lane == 0)
#pragma unroll
        for (int c = 0; c < NCLS; c++) red[wid][c] = p[c];
    __syncthreads();
    if (tid < NCLS) {
        float s = red[0][tid] + red[1][tid] + red[2][tid] + red[3][tid] + rob[tid];
        logits[b * NCLS + tid] = s;
    }
}

// ---------------- loss + accuracy ----------------
__global__ __launch_bounds__(128) void k_loss(
    const float* __restrict__ logits, const int* __restrict__ y,
    float* __restrict__ out)
{
    const int b = threadIdx.x;   // 0..127
    float l[NCLS];
#pragma unroll
    for (int c = 0; c < NCLS; c++) l[c] = logits[b * NCLS + c];
    float m = l[0]; int am = 0;
#pragma unroll
    for (int c = 1; c < NCLS; c++) if (l[c] > m) { m = l[c]; am = c; }
    float s = 0.f;
#pragma unroll
    for (int c = 0; c < NCLS; c++) s += expf(l[c] - m);
    float lse = m + logf(s);
    int yy = y[b];
    float loss_b = lse - l[yy];
    float corr = (am == yy) ? 1.f : 0.f;
    for (int off = 32; off > 0; off >>= 1) {
        loss_b += __shfl_down(loss_b, off, 64);
        corr   += __shfl_down(corr,   off, 64);
    }
    __shared__ float sl[2], sc[2];
    if ((b & 63) == 0) { sl[b >> 6] = loss_b; sc[b >> 6] = corr; }
    __syncthreads();
    if (b == 0) {
        out[0] = (sl[0] + sl[1]) / (float)BN;
        out[1] = sc[0] + sc[1];
    }
}

extern "C" void kernel_launch(void* const* d_in, const int* in_sizes, int n_in,
                              void* d_out, int out_size, void* d_ws, size_t ws_size,
                              hipStream_t stream) {
    const float* x   = (const float*)d_in[0];
    const int*   y   = (const int*)  d_in[1];
    const float* aW  = (const float*)d_in[2];
    const float* ab  = (const float*)d_in[3];
    const float* W1  = (const float*)d_in[4];
    const float* b1  = (const float*)d_in[5];
    const float* W2  = (const float*)d_in[6];
    const float* b2  = (const float*)d_in[7];
    const float* W3  = (const float*)d_in[8];
    const float* b3  = (const float*)d_in[9];
    const float* roW = (const float*)d_in[10];
    const float* rob = (const float*)d_in[11];
    float* out = (float*)d_out;
    float* ws  = (float*)d_ws;

    const size_t ZSZ = (size_t)BN * HCn * NPX;    // 4.19M floats
    float* zb0    = ws;
    float* zb1    = zb0 + ZSZ;
    float* kb0    = zb1 + ZSZ;
    float* kb1    = kb0 + ZSZ;
    float* accb   = kb1 + ZSZ;
    float* logits = accb + ZSZ;
    unsigned short* w2h = (unsigned short*)(logits + 4096);
    unsigned short* w2l = w2h + 589824;
    unsigned short* w1h = w2l + 589824;
    unsigned short* w1l = w1h + 16384;
    unsigned short* w3h = w1l + 16384;
    unsigned short* w3l = w3h + 16384;

    k_packW2<<<2304, 256, 0, stream>>>(W2, w2h, w2l);
    k_packW1<<<64, 256, 0, stream>>>(W1, w1h, w1l);
    k_packW3<<<64, 256, 0, stream>>>(W3, w3h, w3l);
    k_aug<<<BN, 256, 0, stream>>>(x, aW, ab, zb0);

    float* zA = zb0;
    float* zB = zb1;
    for (int p = 0; p < PN; p++) {
        for (int e = 0; e < 4; e++) {
            const int idx = (e == 3 && p + 1 < PN) ? p + 1 : p;
            const float t = (float)p + (e == 0 ? 0.f : (e == 3 ? 1.f : 0.5f));
            const float alpha = (e == 0) ? 0.f : (e == 3 ? 1.f : 0.5f);
            const int mode = (e == 0) ? 0 : (e == 3 ? 2 : 1);
            const float* kbin = (e == 2) ? kb1 : kb0;   // e1:kb0 e2:kb1 e3:kb0
            float* kbout = (e == 1) ? kb1 : kb0;        // e0:kb0 e1:kb1 e2:kb0
            k_fused<<<dim3(8, BN), 512, 0, stream>>>(
                zA, kbin, alpha,
                b1 + (size_t)idx * HHCn, W1 + (size_t)idx * HHCn * 33, t,
                w1h + (size_t)idx * 4096, w1l + (size_t)idx * 4096,
                w2h + (size_t)idx * 147456, w2l + (size_t)idx * 147456,
                b2 + (size_t)idx * HHCn,
                w3h + (size_t)idx * 4096, w3l + (size_t)idx * 4096,
                b3 + (size_t)idx * HCn,
                kbout, accb, zB, mode);
        }
        float* tmp = zA; zA = zB; zB = tmp;
    }

    k_logits<<<BN, 256, 0, stream>>>(zA, roW, rob, logits);
    k_loss<<<1, 128, 0, stream>>>(logits, y, out);
}

// Round 12
// 1946.320 us; speedup vs baseline: 1.2710x; 1.2710x over previous
//
#include <hip/hip_runtime.h>
#include <hip/hip_bf16.h>
#include <math.h>

// Problem constants
#define BN   128      // batch
#define CIN  3
#define HCn  32       // hidden channels (ODE state)
#define HHCn 128      // inner hidden channels
#define NPX  1024     // 32*32
#define PN   4        // pieces
#define NCLS 10

// 4-row strip geometry: 8 strips/image; LDS planes of 8 ic x 16B rows, 208 rows.
#define PLROW 8       // ushorts per plane row (8 ic)
#define PLSZ  1664    // 208 * 8 ushorts per plane
#define H2P   136     // h2 pitch (ushorts): 272B rows

// packed global z-state buffer: per image 2(hi,lo) x 4 planes x 1216 rows x 16B
#define PGPU  9728    // ushorts per plane (1216 rows * 8)
#define IMGU  77824   // ushorts per image (8 * PGPU)

typedef short bf16x8 __attribute__((ext_vector_type(8)));
typedef float f32x4  __attribute__((ext_vector_type(4)));

// ---- fast transcendentals (HW v_exp/v_log/v_rcp; err ~1e-7, threshold 0.2) ----
__device__ __forceinline__ float softplus_f(float x) {
    return fmaxf(x, 0.f) + __logf(1.f + __expf(-fabsf(x)));
}
__device__ __forceinline__ float tanh_fast(float x) {
    float e = __expf(-2.f * fabsf(x));
    float r = 1.f - 2.f * e * __builtin_amdgcn_rcpf(1.f + e);   // tanh(|x|)
    unsigned u = (__float_as_uint(r) & 0x7fffffffu) | (__float_as_uint(x) & 0x80000000u);
    return __uint_as_float(u);
}
__device__ __forceinline__ unsigned int f2bf(float f) {   // RNE fp32->bf16 bits
    unsigned int u = __float_as_uint(f);
    return (u + 0x7fffu + ((u >> 16) & 1u)) >> 16;
}
__device__ __forceinline__ float bf2f(unsigned int h) {
    return __uint_as_float(h << 16);
}
__device__ __forceinline__ void pack2(float a, float b, unsigned int& hi, unsigned int& lo) {
    __hip_bfloat162 h2 = __float22bfloat162_rn(float2{a, b});
    unsigned int h = *reinterpret_cast<unsigned int*>(&h2);
    float ha = __uint_as_float(h << 16);
    float hb = __uint_as_float(h & 0xffff0000u);
    __hip_bfloat162 l2 = __float22bfloat162_rn(float2{a - ha, b - hb});
    hi = h;
    lo = *reinterpret_cast<unsigned int*>(&l2);
}

// ---------------- augment: z fp32 + packed bf16hl(z) into pz0 ----------------
__global__ __launch_bounds__(256) void k_aug(
    const float* __restrict__ x, const float* __restrict__ aW,
    const float* __restrict__ ab, float* __restrict__ z,
    unsigned short* __restrict__ pz0)
{
    const int b = blockIdx.x, tid = threadIdx.x;
    const size_t xb = (size_t)b * CIN * NPX;
    const size_t zb = (size_t)b * HCn * NPX;
    unsigned short* pzi = pz0 + (size_t)b * IMGU;
    float xv[CIN][4];
#pragma unroll
    for (int c = 0; c < CIN; c++)
#pragma unroll
        for (int j = 0; j < 4; j++)
            xv[c][j] = x[xb + c * NPX + tid + 256 * j];
#pragma unroll
    for (int plane = 0; plane < 4; plane++) {
        float v[8][4];
#pragma unroll
        for (int s = 0; s < 8; s++) {
            int o = plane * 8 + s;
            float w0 = aW[o * 3], w1 = aW[o * 3 + 1], w2 = aW[o * 3 + 2], bb = ab[o];
#pragma unroll
            for (int j = 0; j < 4; j++) {
                float vv = fmaf(w0, xv[0][j], fmaf(w1, xv[1][j], fmaf(w2, xv[2][j], bb)));
                v[s][j] = vv;
                z[zb + (size_t)o * NPX + tid + 256 * j] = vv;
            }
        }
#pragma unroll
        for (int j = 0; j < 4; j++) {
            int pix = tid + 256 * j;
            int row = ((pix >> 5) + 1) * 34 + (pix & 31) + 1;
            unsigned int h01, l01, h23, l23, h45, l45, h67, l67;
            pack2(v[0][j], v[1][j], h01, l01);
            pack2(v[2][j], v[3][j], h23, l23);
            pack2(v[4][j], v[5][j], h45, l45);
            pack2(v[6][j], v[7][j], h67, l67);
            *(uint4*)(pzi + (size_t)plane * PGPU + row * 8) = make_uint4(h01, h23, h45, h67);
            *(uint4*)(pzi + (size_t)(4 + plane) * PGPU + row * 8) = make_uint4(l01, l23, l45, l67);
        }
    }
}

// ---------------- pack W2 ----------------
__global__ __launch_bounds__(256) void k_packW2(
    const float* __restrict__ W2, unsigned short* __restrict__ whi,
    unsigned short* __restrict__ wlo)
{
    int t = blockIdx.x * 256 + threadIdx.x;          // < 589824
    int j    = t & 7;
    int lane = (t >> 3) & 63;
    int ocg  = (t >> 9) & 7;
    int kc   = (t >> 12) & 3;
    int p9s  = t >> 14;                              // p*9 + sh
    int sh = p9s % 9, p = p9s / 9;
    int dy = sh / 3, dx = sh % 3;
    int oc = ocg * 16 + (lane & 15);
    int ic = kc * 32 + (lane >> 4) * 8 + j;
    float v = W2[((((size_t)p * HHCn + oc) * HHCn + ic) * 3 + dy) * 3 + dx];
    unsigned int hi = f2bf(v);
    whi[t] = (unsigned short)hi;
    wlo[t] = (unsigned short)f2bf(v - bf2f(hi));
}

// ---------------- pack W1 ----------------
__global__ __launch_bounds__(256) void k_packW1(
    const float* __restrict__ W1, unsigned short* __restrict__ whi,
    unsigned short* __restrict__ wlo)
{
    int t = blockIdx.x * 256 + threadIdx.x;          // < 16384
    int j = t & 7, lane = (t >> 3) & 63, m = (t >> 9) & 1, kc = (t >> 10) & 3, p = t >> 12;
    int oc = kc * 32 + m * 16 + (lane & 15);
    int ic = (lane >> 4) * 8 + j;
    float v = W1[((size_t)p * HHCn + oc) * 33 + 1 + ic];
    unsigned int hi = f2bf(v);
    whi[t] = (unsigned short)hi;
    wlo[t] = (unsigned short)f2bf(v - bf2f(hi));
}

// ---------------- pack W3 ----------------
__global__ __launch_bounds__(256) void k_packW3(
    const float* __restrict__ W3, unsigned short* __restrict__ whi,
    unsigned short* __restrict__ wlo)
{
    int t = blockIdx.x * 256 + threadIdx.x;          // < 16384
    int j = t & 7, lane = (t >> 3) & 63, kk = (t >> 9) & 3, m = (t >> 11) & 1, p = t >> 12;
    int st = m * 16 + (lane & 15);
    int ic = kk * 32 + (lane >> 4) * 8 + j;
    float v = W3[((size_t)p * HCn + st) * HHCn + ic];
    unsigned int hi = f2bf(v);
    whi[t] = (unsigned short)hi;
    wlo[t] = (unsigned short)f2bf(v - bf2f(hi));
}

// ---------------- fused f-eval, packed-state I/O, dbuf-pipelined ------------
// grid (8 strips, BN), 512 thr. Staging = pure uint4 copy from pz_in.
// Epilogue writes packed(z + alpha_next*k) (or packed z_new) into pz_out.
__global__ __launch_bounds__(512, 4) void k_fused(
    const float* __restrict__ z_in, const unsigned short* __restrict__ pz_in,
    const float* __restrict__ b1p, const float* __restrict__ W1t, float t,
    const unsigned short* __restrict__ w1h, const unsigned short* __restrict__ w1l,
    const unsigned short* __restrict__ w2h, const unsigned short* __restrict__ w2l,
    const float* __restrict__ b2p,
    const unsigned short* __restrict__ w3h, const unsigned short* __restrict__ w3l,
    const float* __restrict__ b3p,
    float* __restrict__ accb, float* __restrict__ z_out,
    unsigned short* __restrict__ pz_out, float alpha_next, int mode)
{
    const int strip = blockIdx.x, b = blockIdx.y;
    const int tid = threadIdx.x, lane = tid & 63, wid = tid >> 6;
    const int ln15 = lane & 15, lg = lane >> 4;
    const int kl8 = lg * 8, kl4 = lg * 4;

    __shared__ __align__(16) unsigned short S[39936];   // 79.87 KB
    unsigned short* zinh = S;                            // 4 planes * 1664
    unsigned short* zinl = S + 6656;
    unsigned short* xh0  = S + 13312;
    unsigned short* xl0  = S + 19968;
    unsigned short* xh1  = S + 26624;
    unsigned short* xl1  = S + 33280;
    unsigned short* h2qh = S;                            // alias zin (freed)
    unsigned short* h2ql = S + 8704;

    // ---- phase 0: stage zin: straight uint4 copy of pre-packed state ----
    {
        const unsigned short* src0 = pz_in + (size_t)b * IMGU;
        const int rowoff = strip * 136;
#pragma unroll
        for (int i = 0; i < 4; i++) {
            int c = tid + 512 * i;                    // chunk < 1664
            if (c < 1664) {
                int region = c / 208;                 // hl*4 + plane
                int row = c - region * 208;
                uint4 d = *(const uint4*)(src0 + (size_t)region * PGPU + (size_t)(rowoff + row) * 8);
                *(uint4*)(S + region * 1664 + row * 8) = d;   // zinh/zinl contiguous
            }
        }
    }

    const int wocg = (wid & 3) * 2;          // conv3: oc pair base (16-oc units)
    const int wph  = (wid >> 2) * 64;        // conv3: px half (64 px)
    const int strip0 = strip * 4;
    int boff[4];
#pragma unroll
    for (int f = 0; f < 4; f++) {
        int pxl = wph + f * 16 + ln15;
        boff[f] = lg * PLSZ + ((pxl >> 5) * 34 + (pxl & 31)) * PLROW;
    }

    f32x4 acc[2][4];
#pragma unroll
    for (int o = 0; o < 2; o++)
#pragma unroll
        for (int f = 0; f < 4; f++) acc[o][f] = (f32x4)(0.f);

    f32x4 c1[2][2];

    // conv1 MFMA (16x16x32) for chunk kc -> c1 (reads zin; stable all loop)
    auto do_conv1 = [&](int kc) {
        const unsigned short* w1hb = w1h + (size_t)kc * 1024 + lane * 8;
        const unsigned short* w1lb = w1l + (size_t)kc * 1024 + lane * 8;
        bf16x8 a1h0 = *(const bf16x8*)w1hb, a1h1 = *(const bf16x8*)(w1hb + 512);
        bf16x8 a1l0 = *(const bf16x8*)w1lb, a1l1 = *(const bf16x8*)(w1lb + 512);
#pragma unroll
        for (int m = 0; m < 2; m++)
#pragma unroll
            for (int ni = 0; ni < 2; ni++) c1[m][ni] = (f32x4)(0.f);
#pragma unroll
        for (int ni = 0; ni < 2; ni++) {
            int n = wid + 8 * ni;
            if (ni == 0 || wid < 5) {
                int roff = lg * PLSZ + (n * 16 + ln15) * PLROW;
                bf16x8 bh = *(const bf16x8*)(zinh + roff);
                bf16x8 bl = *(const bf16x8*)(zinl + roff);
                c1[0][ni] = __builtin_amdgcn_mfma_f32_16x16x32_bf16(a1h0, bh, c1[0][ni], 0, 0, 0);
                c1[0][ni] = __builtin_amdgcn_mfma_f32_16x16x32_bf16(a1h0, bl, c1[0][ni], 0, 0, 0);
                c1[0][ni] = __builtin_amdgcn_mfma_f32_16x16x32_bf16(a1l0, bh, c1[0][ni], 0, 0, 0);
                c1[1][ni] = __builtin_amdgcn_mfma_f32_16x16x32_bf16(a1h1, bh, c1[1][ni], 0, 0, 0);
                c1[1][ni] = __builtin_amdgcn_mfma_f32_16x16x32_bf16(a1h1, bl, c1[1][ni], 0, 0, 0);
                c1[1][ni] = __builtin_amdgcn_mfma_f32_16x16x32_bf16(a1l1, bh, c1[1][ni], 0, 0, 0);
            }
        }
    };

    // softplus + pack + write X chunk kc into (xh_, xl_)
    auto do_writeX = [&](int kc, unsigned short* xh_, unsigned short* xl_) {
        float eb[2][4];
#pragma unroll
        for (int m = 0; m < 2; m++)
#pragma unroll
            for (int r = 0; r < 4; r++) {
                int oc = kc * 32 + m * 16 + kl4 + r;
                eb[m][r] = b1p[oc] + t * W1t[oc * 33];
            }
#pragma unroll
        for (int ni = 0; ni < 2; ni++) {
            int n = wid + 8 * ni;
            if (ni == 0 || wid < 5) {
                int ppad = n * 16 + ln15;
                int prow = ppad / 34, pcol = ppad - prow * 34;
                int gy = strip0 + prow - 1;
                bool zero = (pcol == 0) || (pcol == 33) || (gy < 0) || (gy >= 32);
#pragma unroll
                for (int m = 0; m < 2; m++) {
                    float v[4];
#pragma unroll
                    for (int r = 0; r < 4; r++)
                        v[r] = zero ? 0.f : softplus_f(c1[m][ni][r] + eb[m][r]);
                    unsigned int h01, l01, h23, l23;
                    pack2(v[0], v[1], h01, l01);
                    pack2(v[2], v[3], h23, l23);
                    int off = (m * 2 + (kl4 >> 3)) * PLSZ + ppad * PLROW + (kl4 & 7);
                    *(uint2*)(xh_ + off) = make_uint2(h01, h23);
                    *(uint2*)(xl_ + off) = make_uint2(l01, l23);
                }
            }
        }
    };

    // conv3 partial for chunk kc from (xh_, xl_)
    auto do_conv3 = [&](int kc, const unsigned short* xh_, const unsigned short* xl_) {
#pragma unroll
        for (int sh = 0; sh < 9; sh++) {
            const size_t wbase = ((size_t)(sh * 4 + kc) * 8 + wocg) * 512 + lane * 8;
            bf16x8 ah0 = *(const bf16x8*)(w2h + wbase);
            bf16x8 al0 = *(const bf16x8*)(w2l + wbase);
            bf16x8 ah1 = *(const bf16x8*)(w2h + wbase + 512);
            bf16x8 al1 = *(const bf16x8*)(w2l + wbase + 512);
            const int soff = ((sh / 3) * 34 + (sh % 3)) * PLROW;
#pragma unroll
            for (int f = 0; f < 4; f++) {
                bf16x8 bh = *(const bf16x8*)(xh_ + boff[f] + soff);
                bf16x8 bl = *(const bf16x8*)(xl_ + boff[f] + soff);
                acc[0][f] = __builtin_amdgcn_mfma_f32_16x16x32_bf16(ah0, bh, acc[0][f], 0, 0, 0);
                acc[0][f] = __builtin_amdgcn_mfma_f32_16x16x32_bf16(ah0, bl, acc[0][f], 0, 0, 0);
                acc[0][f] = __builtin_amdgcn_mfma_f32_16x16x32_bf16(al0, bh, acc[0][f], 0, 0, 0);
                acc[1][f] = __builtin_amdgcn_mfma_f32_16x16x32_bf16(ah1, bh, acc[1][f], 0, 0, 0);
                acc[1][f] = __builtin_amdgcn_mfma_f32_16x16x32_bf16(ah1, bl, acc[1][f], 0, 0, 0);
                acc[1][f] = __builtin_amdgcn_mfma_f32_16x16x32_bf16(al1, bh, acc[1][f], 0, 0, 0);
            }
        }
    };

    __syncthreads();                 // zin staged
    do_conv1(0);
    do_writeX(0, xh0, xl0);          // X0 <- chunk 0
    __syncthreads();

    do_conv1(1); do_writeX(1, xh1, xl1); do_conv3(0, xh0, xl0);
    __syncthreads();
    do_conv1(2); do_writeX(2, xh0, xl0); do_conv3(1, xh1, xl1);
    __syncthreads();
    do_conv1(3); do_writeX(3, xh1, xl1); do_conv3(2, xh0, xl0);
    __syncthreads();
    do_conv3(3, xh1, xl1);

    // ---- convw3 + RK4 + packed-state epilogue, per 64-px half ----
    float bb2[2][4];
#pragma unroll
    for (int o2 = 0; o2 < 2; o2++)
#pragma unroll
        for (int r = 0; r < 4; r++)
            bb2[o2][r] = b2p[(wocg + o2) * 16 + kl4 + r];

    const size_t obB = (size_t)b * HCn * NPX + strip * 128;
    const int m3 = wid & 1, n4 = wid >> 1;
    float bb3[4];
#pragma unroll
    for (int r = 0; r < 4; r++) bb3[r] = b3p[m3 * 16 + kl4 + r];

#pragma unroll
    for (int q = 0; q < 2; q++) {
        __syncthreads();   // q=0: conv3(3) done (zin/X0 free)
        if ((wid >> 2) == q) {             // owning px-half group writes h2 half
#pragma unroll
            for (int o2 = 0; o2 < 2; o2++)
#pragma unroll
                for (int f2 = 0; f2 < 4; f2++) {
                    f32x4 a = acc[o2][f2];
                    float v[4];
#pragma unroll
                    for (int r = 0; r < 4; r++) v[r] = softplus_f(a[r] + bb2[o2][r]);
                    unsigned int h01, l01, h23, l23;
                    pack2(v[0], v[1], h01, l01);
                    pack2(v[2], v[3], h23, l23);
                    int off = (f2 * 16 + ln15) * H2P + (wocg + o2) * 16 + kl4;
                    *(uint2*)(h2qh + off) = make_uint2(h01, h23);
                    *(uint2*)(h2ql + off) = make_uint2(l01, l23);
                }
        }
        __syncthreads();
        // convw3: [32st x 128K] x h2q[128K x 64px]; 1 tile per wave (16x16x32)
        f32x4 c3 = (f32x4)(0.f);
#pragma unroll
        for (int kk = 0; kk < 4; kk++) {
            const unsigned short* a3hb = w3h + (size_t)(m3 * 4 + kk) * 512 + lane * 8;
            const unsigned short* a3lb = w3l + (size_t)(m3 * 4 + kk) * 512 + lane * 8;
            bf16x8 a3h = *(const bf16x8*)a3hb;
            bf16x8 a3l = *(const bf16x8*)a3lb;
            bf16x8 bh = *(const bf16x8*)(h2qh + (n4 * 16 + ln15) * H2P + kk * 32 + kl8);
            bf16x8 bl = *(const bf16x8*)(h2ql + (n4 * 16 + ln15) * H2P + kk * 32 + kl8);
            c3 = __builtin_amdgcn_mfma_f32_16x16x32_bf16(a3h, bh, c3, 0, 0, 0);
            c3 = __builtin_amdgcn_mfma_f32_16x16x32_bf16(a3h, bl, c3, 0, 0, 0);
            c3 = __builtin_amdgcn_mfma_f32_16x16x32_bf16(a3l, bh, c3, 0, 0, 0);
        }
        // RK4 update + packed-state write for next eval
        const int st0 = m3 * 16 + kl4;
        const int pix = strip * 128 + q * 64 + n4 * 16 + ln15;
        const int prow_g = ((pix >> 5) + 1) * 34 + (pix & 31) + 1;
        float pk[4];
#pragma unroll
        for (int r = 0; r < 4; r++) {
            int st = st0 + r;
            float v = tanh_fast(c3[r] + bb3[r]);
            size_t i = obB + (size_t)st * NPX + q * 64 + n4 * 16 + ln15;
            float zv = z_in[i];
            if (mode == 0)      { accb[i] = v;           pk[r] = fmaf(alpha_next, v, zv); }
            else if (mode == 1) { accb[i] += 2.f * v;    pk[r] = fmaf(alpha_next, v, zv); }
            else { float zn = zv + (accb[i] + v) * (1.f / 6.f); z_out[i] = zn; pk[r] = zn; }
        }
        unsigned int h01, l01, h23, l23;
        pack2(pk[0], pk[1], h01, l01);
        pack2(pk[2], pk[3], h23, l23);
        unsigned short* dsth = pz_out + (size_t)b * IMGU + (size_t)(st0 >> 3) * PGPU
                               + (size_t)prow_g * 8 + (st0 & 7);
        *(uint2*)dsth = make_uint2(h01, h23);
        *(uint2*)(dsth + (size_t)4 * PGPU) = make_uint2(l01, l23);
    }
}

// ---------------- readout ----------------
__global__ __launch_bounds__(256) void k_logits(
    const float* __restrict__ z, const float* __restrict__ roW,
    const float* __restrict__ rob, float* __restrict__ logits)
{
    const int b = blockIdx.x, tid = threadIdx.x;
    float p[NCLS];
#pragma unroll
    for (int c = 0; c < NCLS; c++) p[c] = 0.f;
    const float* zp = z + (size_t)b * 32768;
    for (int i = tid; i < 32768; i += 256) {
        float zv = zp[i];
#pragma unroll
        for (int c = 0; c < NCLS; c++) p[c] = fmaf(zv, roW[(size_t)c * 32768 + i], p[c]);
    }
#pragma unroll
    for (int c = 0; c < NCLS; c++)
        for (int off = 32; off > 0; off >>= 1) p[c] += __shfl_down(p[c], off, 64);
    __shared__ float red[4][NCLS];
    int wid = tid >> 6, lane = tid & 63;
    if (lane == 0)
#pragma unroll
        for (int c = 0; c < NCLS; c++) red[wid][c] = p[c];
    __syncthreads();
    if (tid < NCLS) {
        float s = red[0][tid] + red[1][tid] + red[2][tid] + red[3][tid] + rob[tid];
        logits[b * NCLS + tid] = s;
    }
}

// ---------------- loss + accuracy ----------------
__global__ __launch_bounds__(128) void k_loss(
    const float* __restrict__ logits, const int* __restrict__ y,
    float* __restrict__ out)
{
    const int b = threadIdx.x;   // 0..127
    float l[NCLS];
#pragma unroll
    for (int c = 0; c < NCLS; c++) l[c] = logits[b * NCLS + c];
    float m = l[0]; int am = 0;
#pragma unroll
    for (int c = 1; c < NCLS; c++) if (l[c] > m) { m = l[c]; am = c; }
    float s = 0.f;
#pragma unroll
    for (int c = 0; c < NCLS; c++) s += expf(l[c] - m);
    float lse = m + logf(s);
    int yy = y[b];
    float loss_b = lse - l[yy];
    float corr = (am == yy) ? 1.f : 0.f;
    for (int off = 32; off > 0; off >>= 1) {
        loss_b += __shfl_down(loss_b, off, 64);
        corr   += __shfl_down(corr,   off, 64);
    }
    __shared__ float sl[2], sc[2];
    if ((b & 63) == 0) { sl[b >> 6] = loss_b; sc[b >> 6] = corr; }
    __syncthreads();
    if (b == 0) {
        out[0] = (sl[0] + sl[1]) / (float)BN;
        out[1] = sc[0] + sc[1];
    }
}

extern "C" void kernel_launch(void* const* d_in, const int* in_sizes, int n_in,
                              void* d_out, int out_size, void* d_ws, size_t ws_size,
                              hipStream_t stream) {
    const float* x   = (const float*)d_in[0];
    const int*   y   = (const int*)  d_in[1];
    const float* aW  = (const float*)d_in[2];
    const float* ab  = (const float*)d_in[3];
    const float* W1  = (const float*)d_in[4];
    const float* b1  = (const float*)d_in[5];
    const float* W2  = (const float*)d_in[6];
    const float* b2  = (const float*)d_in[7];
    const float* W3  = (const float*)d_in[8];
    const float* b3  = (const float*)d_in[9];
    const float* roW = (const float*)d_in[10];
    const float* rob = (const float*)d_in[11];
    float* out = (float*)d_out;
    float* ws  = (float*)d_ws;

    const size_t ZSZ = (size_t)BN * HCn * NPX;    // 4.19M floats
    float* zb0    = ws;
    float* zb1    = zb0 + ZSZ;
    float* accb   = zb1 + ZSZ;
    float* logits = accb + ZSZ;
    unsigned short* w2h = (unsigned short*)(logits + 4096);
    unsigned short* w2l = w2h + 589824;
    unsigned short* w1h = w2l + 589824;
    unsigned short* w1l = w1h + 16384;
    unsigned short* w3h = w1l + 16384;
    unsigned short* w3l = w3h + 16384;
    unsigned short* pz0 = w3l + 16384;
    unsigned short* pz1 = pz0 + (size_t)BN * IMGU;

    // zero packed-state borders (interior rewritten every eval; borders stay 0)
    hipMemsetAsync(pz0, 0, (size_t)2 * BN * IMGU * sizeof(unsigned short), stream);

    k_packW2<<<2304, 256, 0, stream>>>(W2, w2h, w2l);
    k_packW1<<<64, 256, 0, stream>>>(W1, w1h, w1l);
    k_packW3<<<64, 256, 0, stream>>>(W3, w3h, w3l);
    k_aug<<<BN, 256, 0, stream>>>(x, aW, ab, zb0, pz0);

    float* zA = zb0;
    float* zB = zb1;
    unsigned short* pza = pz0;
    unsigned short* pzb = pz1;
    for (int ge = 0; ge < 16; ge++) {
        const int p = ge >> 2, e = ge & 3;
        const int idx = (e == 3 && p + 1 < PN) ? p + 1 : p;
        const float t = (float)p + (e == 0 ? 0.f : (e == 3 ? 1.f : 0.5f));
        const int mode = (e == 0) ? 0 : (e == 3 ? 2 : 1);
        const float alpha_next = (e == 2) ? 1.f : ((e == 3) ? 0.f : 0.5f);
        k_fused<<<dim3(8, BN), 512, 0, stream>>>(
            zA, pza,
            b1 + (size_t)idx * HHCn, W1 + (size_t)idx * HHCn * 33, t,
            w1h + (size_t)idx * 4096, w1l + (size_t)idx * 4096,
            w2h + (size_t)idx * 147456, w2l + (size_t)idx * 147456,
            b2 + (size_t)idx * HHCn,
            w3h + (size_t)idx * 4096, w3l + (size_t)idx * 4096,
            b3 + (size_t)idx * HCn,
            accb, zB, pzb, alpha_next, mode);
        unsigned short* tp = pza; pza = pzb; pzb = tp;
        if (e == 3) { float* tz = zA; zA = zB; zB = tz; }
    }

    k_logits<<<BN, 256, 0, stream>>>(zA, roW, rob, logits);
    k_loss<<<1, 128, 0, stream>>>(logits, y, out);
}